// Round 2
// baseline (1065.016 us; speedup 1.0000x reference)
//
#include <hip/hip_runtime.h>

// KCenterSampler: farthest-point sampling, exact arithmetic replication of the
// JAX reference (sq + sq - 2*dot formulation, f32 carry, first-index argmax).
//
// Shapes (fixed by setup_inputs): B=4,T=16,H=28,W=28,C=35
//   Bt = 8 segments, N = 6272 points, C = 35 dims, k_ = 128 selections/segment.
// Outputs (concatenated, all read back as float32):
//   patches:        4*256*32 = 32768 floats
//   sampling_index: 4*256    =  1024 floats (integer values stored as f32)

#define NPTS 6272
#define CDIM 35
#define BT   8
#define KSEL 128
#define THW  12544   // T*H*W
#define BLK_FPS 1024

// ---------------------------------------------------------------------------
// Kernel 1: transpose x -> channel-major xT[b][c][j], compute sq[b][j].
// sq order: strict sequential (x*x then add), no contraction — mimics XLA CPU
// f32 reduce with fast-math off.
// ---------------------------------------------------------------------------
__global__ __launch_bounds__(256) void prep_kernel(const float* __restrict__ x,
                                                   float* __restrict__ xT,
                                                   float* __restrict__ sq) {
  int b = blockIdx.y;
  int j = blockIdx.x * 256 + (int)threadIdx.x;
  if (j >= NPTS) return;
  const float* p = x + ((size_t)b * NPTS + j) * CDIM;
  float acc = 0.0f;
  {
#pragma clang fp contract(off)
#pragma unroll
    for (int c = 0; c < CDIM; ++c) {
      float v = p[c];
      xT[((size_t)b * CDIM + c) * NPTS + j] = v;
      acc = acc + v * v;
    }
  }
  sq[b * NPTS + j] = acc;
}

// ---------------------------------------------------------------------------
// Kernel 2: persistent FPS, one block per segment. distance + sq in LDS.
// Per step: d(f,j) for all j (coalesced channel-major reads, L2-resident),
// f32 min-carry, block-wide argmax with first-index tie-break.
// ---------------------------------------------------------------------------
__global__ __launch_bounds__(BLK_FPS) void fps_kernel(const float* __restrict__ x,
                                                      const float* __restrict__ xT,
                                                      const float* __restrict__ sq,
                                                      const int* __restrict__ init_,
                                                      int* __restrict__ out_idx) {
  __shared__ float dist_s[NPTS];
  __shared__ float sq_s[NPTS];
  __shared__ float xf_s[CDIM];
  __shared__ float rv[16];
  __shared__ int   ri[16];
  __shared__ int   far_s;

  const int b = blockIdx.x;
  const int tid = (int)threadIdx.x;

  for (int j = tid; j < NPTS; j += BLK_FPS) {
    dist_s[j] = 50000.0f;              // FILL_DIST
    sq_s[j] = sq[b * NPTS + j];
  }
  if (tid == 0) {
    int f = init_[b] % NPTS;
    if (f < 0) f += NPTS;              // jnp.remainder semantics (inputs >=0 anyway)
    far_s = f;
    out_idx[b * KSEL] = f;
  }
  __syncthreads();
  int far = far_s;
  const float* xTb = xT + (size_t)b * CDIM * NPTS;

  for (int step = 1; step < KSEL; ++step) {
    if (tid < CDIM)
      xf_s[tid] = x[((size_t)b * NPTS + far) * CDIM + tid];
    __syncthreads();

    const float sqf = sq_s[far];
    float best_v = -3.0f;
    int   best_i = 0x7fffffff;

    for (int j = tid; j < NPTS; j += BLK_FPS) {
      float dot = 0.0f;
#pragma unroll
      for (int c = 0; c < CDIM; ++c)
        dot = __builtin_fmaf(xf_s[c], xTb[c * NPTS + j], dot);  // Eigen-style k-sequential FMA
      float d2;
      {
#pragma clang fp contract(off)
        d2 = (sqf + sq_s[j]) - 2.0f * dot;   // exact reference formula order
      }
      d2 = fmaxf(d2, 0.0f);
      float d = __fsqrt_rn(d2);              // correctly-rounded, matches CPU sqrtss
      d = (j == far) ? -1.0f : d;            // diagonal = -1
      float nd = fminf(d, dist_s[j]);        // f32 carry, as in reference
      dist_s[j] = nd;
      if (nd > best_v || (nd == best_v && j < best_i)) { best_v = nd; best_i = j; }
    }

    // wave-level argmax (first-index tie-break)
#pragma unroll
    for (int off = 32; off > 0; off >>= 1) {
      float ov = __shfl_down(best_v, off);
      int   oi = __shfl_down(best_i, off);
      if (ov > best_v || (ov == best_v && oi < best_i)) { best_v = ov; best_i = oi; }
    }
    const int wid = tid >> 6, lane = tid & 63;
    if (lane == 0) { rv[wid] = best_v; ri[wid] = best_i; }
    __syncthreads();
    if (tid < 64) {
      best_v = (tid < 16) ? rv[tid] : -4.0f;
      best_i = (tid < 16) ? ri[tid] : 0x7fffffff;
#pragma unroll
      for (int off = 8; off > 0; off >>= 1) {
        float ov = __shfl_down(best_v, off);
        int   oi = __shfl_down(best_i, off);
        if (ov > best_v || (ov == best_v && oi < best_i)) { best_v = ov; best_i = oi; }
      }
      if (tid == 0) { far_s = best_i; out_idx[b * KSEL + step] = best_i; }
    }
    __syncthreads();
    far = far_s;
  }
}

// ---------------------------------------------------------------------------
// Kernel 3: gather patches (first 32 channels) + write indices (as f32).
// ---------------------------------------------------------------------------
__global__ __launch_bounds__(256) void gather_kernel(const float* __restrict__ x,
                                                     const int* __restrict__ out_idx,
                                                     float* __restrict__ patches,
                                                     float* __restrict__ sidx) {
  const int b = blockIdx.x;          // 0..3
  const int m = (int)threadIdx.x;    // 0..255
  const int td = m >> 7;             // time segment 0/1
  const int i  = m & 127;
  const int li = out_idx[(b * 2 + td) * KSEL + i];
  const int gi = li + td * NPTS;     // + per-segment offset
  sidx[b * 256 + m] = (float)gi;
  const float* src = x + ((size_t)b * THW + gi) * CDIM;
  float* dst = patches + ((size_t)b * 256 + m) * 32;
#pragma unroll
  for (int c = 0; c < 32; ++c) dst[c] = src[c];   // first C-3 channels
}

extern "C" void kernel_launch(void* const* d_in, const int* in_sizes, int n_in,
                              void* d_out, int out_size, void* d_ws, size_t ws_size,
                              hipStream_t stream) {
  const float* x    = (const float*)d_in[0];
  const int*   init = (const int*)d_in[1];
  (void)in_sizes; (void)n_in; (void)out_size; (void)ws_size;

  // workspace layout (floats): xT [BT*CDIM*NPTS] | sq [BT*NPTS] | idx [BT*KSEL ints]
  float* xT = (float*)d_ws;
  float* sq = xT + (size_t)BT * CDIM * NPTS;
  int*   idx = (int*)(sq + (size_t)BT * NPTS);

  float* patches = (float*)d_out;
  float* sidx    = patches + (size_t)4 * 256 * 32;

  dim3 g1((NPTS + 255) / 256, BT);
  hipLaunchKernelGGL(prep_kernel, g1, dim3(256), 0, stream, x, xT, sq);
  hipLaunchKernelGGL(fps_kernel, dim3(BT), dim3(BLK_FPS), 0, stream, x, xT, sq, init, idx);
  hipLaunchKernelGGL(gather_kernel, dim3(4), dim3(256), 0, stream, x, idx, patches, sidx);
}